// Round 18
// baseline (399.531 us; speedup 1.0000x reference)
//
#include <hip/hip_runtime.h>
#include <hip/hip_fp8.h>

#define NROWS 8192
#define DDIM  512
#define INV_TAU 14.285714285714286f

typedef float f32x16 __attribute__((ext_vector_type(16)));
typedef int   i32x4  __attribute__((ext_vector_type(4)));
typedef int   i32x8  __attribute__((ext_vector_type(8)));

__device__ static inline unsigned char f2e4(float f) {
  __hip_fp8_e4m3 h(f); return (unsigned char)h.__x;
}

__device__ static inline void load_lds16(const void* g, void* l) {
  __builtin_amdgcn_global_load_lds(
      (const __attribute__((address_space(1))) void*)g,
      (__attribute__((address_space(3))) void*)l, 16, 0, 0);
}

// ---------------- layout ------------------------------------------------------
// Fragment-major panels (R9-R17-verified): panel p = rows [32p,32p+32), 16KB.
// Unit u (1 KB) holds k-blocks kb=2u,2u+1 in lane order (lane = h*32 + r).
// Chunk c (8 fp8) of row r: p*16384 + (c>>2)*1024 + ((c&1)*32+r)*16 + ((c>>1)&1)*8.
// At lane-slot (h,byte) the stored k is row-independent and bijective, so the
// k-permutation cancels between A and B operands for ANY MFMA K-width.

// ---------------- normalize + zero accumulators -------------------------------
__global__ __launch_bounds__(256) void norm_kernel(
    const float* __restrict__ zi, const float* __restrict__ zj,
    unsigned char* __restrict__ ziN, unsigned char* __restrict__ zjN,
    float* __restrict__ sums /* row_sum..col_sum, 16384 floats */) {
  if (blockIdx.x < 64) sums[blockIdx.x * 256 + threadIdx.x] = 0.0f;
  int rid = blockIdx.x * 4 + (threadIdx.x >> 6);   // 0..16383
  int lane = threadIdx.x & 63;
  const float* src;
  unsigned char* dstbase;
  int row;
  if (rid < NROWS) { src = zi + (size_t)rid * DDIM; dstbase = ziN; row = rid; }
  else             { src = zj + (size_t)(rid - NROWS) * DDIM; dstbase = zjN; row = rid - NROWS; }
  float4 v0 = *(const float4*)(src + lane * 8);
  float4 v1 = *(const float4*)(src + lane * 8 + 4);
  float ss = v0.x*v0.x + v0.y*v0.y + v0.z*v0.z + v0.w*v0.w
           + v1.x*v1.x + v1.y*v1.y + v1.z*v1.z + v1.w*v1.w;
  #pragma unroll
  for (int off = 1; off < 64; off <<= 1) ss += __shfl_xor(ss, off);
  float scale = 1.0f / fmaxf(sqrtf(ss), 1e-8f);
  unsigned long long w = 0;
  w |= (unsigned long long)f2e4(v0.x * scale);
  w |= (unsigned long long)f2e4(v0.y * scale) << 8;
  w |= (unsigned long long)f2e4(v0.z * scale) << 16;
  w |= (unsigned long long)f2e4(v0.w * scale) << 24;
  w |= (unsigned long long)f2e4(v1.x * scale) << 32;
  w |= (unsigned long long)f2e4(v1.y * scale) << 40;
  w |= (unsigned long long)f2e4(v1.z * scale) << 48;
  w |= (unsigned long long)f2e4(v1.w * scale) << 56;
  int p = row >> 5, r = row & 31, c = lane;     // chunk index = lane
  *(unsigned long long*)(dstbase + (size_t)p * 16384 + (c >> 2) * 1024 +
                         ((c & 1) * 32 + r) * 16 + ((c >> 1) & 1) * 8) = w;
}

// ---------------- fused sim GEMM + exp + row/col sum + diag pos ---------------
// R13/R17-exact schedule: 128x128 block, 4 waves 2x2 (64x64/wave), BK=64,
// dbuf 32KB, stage(t+1) -> vmcnt(4) -> barrier -> ds_read+MFMA -> barrier.
// MFMA inner: 4x mfma_scale_f32_32x32x64_f8f6f4 (unit E8M0 scales = 1.0)
// instead of 16x 32x32x16 -- K=64/instr at ~2x rate halves the serial MFMA
// window.  C/D layout shape-determined -> epilogue unchanged.
__global__ __launch_bounds__(256, 4) void sim_lds(
    const unsigned char* __restrict__ Ap, const unsigned char* __restrict__ Bp,
    float* __restrict__ row_sum, float* __restrict__ col_sum,
    float* __restrict__ pos) {
  // buffer: A[4 panels][2 units][1KB] = 8KB, B same at +8192.  2 buffers.
  __shared__ __align__(16) unsigned char lds[32768];

  const int tid  = threadIdx.x;
  const int lane = tid & 63;
  const int wid  = tid >> 6;
  const int wr   = wid >> 1, wc = wid & 1;   // 2x2 waves, 64x64 each
  const int cl   = lane & 31;                // operand row / C col
  const int h    = lane >> 5;
  // XCD-chunked swizzle (R10): xcd owns by in [8*xcd, 8*xcd+8)
  const int orig = blockIdx.x;               // 0..4095
  const int xcd  = orig & 7;
  const int seq  = orig >> 3;                // 0..511
  const int by   = xcd * 8 + (seq & 7);
  const int bx   = seq >> 3;                 // 0..63
  const int brow = by * 128, bcol = bx * 128;

  f32x16 acc[2][2] = {};

  // staging sources: wave w stages panel w of A and of B
  const unsigned char* gA = Ap + (size_t)(by * 4 + wid) * 16384 + lane * 16;
  const unsigned char* gB = Bp + (size_t)(bx * 4 + wid) * 16384 + lane * 16;
  char* ldsA = (char*)lds + wid * 2048 + lane * 16;          // + buf + kk*1024
  char* ldsB = (char*)lds + 8192 + wid * 2048 + lane * 16;

  auto stage = [&](int t) {   // tile t: units 2t, 2t+1 -> buf[t&1]
    const int buf = (t & 1) * 16384;
    const int u0  = (2 * t) << 10;
    load_lds16(gA + u0,        ldsA + buf);
    load_lds16(gA + u0 + 1024, ldsA + buf + 1024);
    load_lds16(gB + u0,        ldsB + buf);
    load_lds16(gB + u0 + 1024, ldsB + buf + 1024);
  };

  // frag-read bases (linear: unit base + lane*16)
  const char* rA = (const char*)lds + wr * 2 * 2048 + lane * 16;
  const char* rB = (const char*)lds + 8192 + wc * 2 * 2048 + lane * 16;

  // prologue: stage tile 0
  stage(0);

  #pragma unroll
  for (int t = 0; t < 8; ++t) {
    if (t < 7) {
      stage(t + 1);
      asm volatile("s_waitcnt vmcnt(4)" ::: "memory");  // tile t landed; t+1 in flight
    } else {
      asm volatile("s_waitcnt vmcnt(0)" ::: "memory");
    }
    __builtin_amdgcn_s_barrier();
    const int buf = (t & 1) * 16384;
    i32x8 av[2], bv[2];
    #pragma unroll
    for (int i = 0; i < 2; ++i) {
      i32x4 alo = *(const i32x4*)(rA + buf + i * 2048);
      i32x4 ahi = *(const i32x4*)(rA + buf + i * 2048 + 1024);
      av[i] = __builtin_shufflevector(alo, ahi, 0, 1, 2, 3, 4, 5, 6, 7);
      i32x4 blo = *(const i32x4*)(rB + buf + i * 2048);
      i32x4 bhi = *(const i32x4*)(rB + buf + i * 2048 + 1024);
      bv[i] = __builtin_shufflevector(blo, bhi, 0, 1, 2, 3, 4, 5, 6, 7);
    }
    // unit scales (E8M0 0x7F = 2^0) -> identical math to non-scaled fp8
    acc[0][0] = __builtin_amdgcn_mfma_scale_f32_32x32x64_f8f6f4(
        av[0], bv[0], acc[0][0], 0, 0, 0, 0x7F7F7F7F, 0, 0x7F7F7F7F);
    acc[0][1] = __builtin_amdgcn_mfma_scale_f32_32x32x64_f8f6f4(
        av[0], bv[1], acc[0][1], 0, 0, 0, 0x7F7F7F7F, 0, 0x7F7F7F7F);
    acc[1][0] = __builtin_amdgcn_mfma_scale_f32_32x32x64_f8f6f4(
        av[1], bv[0], acc[1][0], 0, 0, 0, 0x7F7F7F7F, 0, 0x7F7F7F7F);
    acc[1][1] = __builtin_amdgcn_mfma_scale_f32_32x32x64_f8f6f4(
        av[1], bv[1], acc[1][1], 0, 0, 0, 0x7F7F7F7F, 0, 0x7F7F7F7F);
    __builtin_amdgcn_s_barrier();   // WAR: reads done before next overwrite
  }

  // epilogue (verified 32x32 C layout: col=cl, row=(reg&3)+8*(reg>>2)+4*h)
  // diag: pos[i] = dot * INV_TAU (identical fp8 values as lse path), e -> 0
  const float Cc = INV_TAU * 1.4426950408889634f;
  #pragma unroll
  for (int mf = 0; mf < 2; ++mf)
    #pragma unroll
    for (int nf = 0; nf < 2; ++nf) {
      int gj = bcol + wc * 64 + nf * 32 + cl;
      #pragma unroll
      for (int reg = 0; reg < 16; ++reg) {
        int gi = brow + wr * 64 + mf * 32 + (reg & 3) + 8 * (reg >> 2) + 4 * h;
        float d = acc[mf][nf][reg];
        float e = exp2f((d - 1.0f) * Cc);
        if (gi == gj) pos[gi] = d * INV_TAU;
        acc[mf][nf][reg] = (gi == gj) ? 0.0f : e;
      }
    }
  #pragma unroll
  for (int nf = 0; nf < 2; ++nf) {
    float cs = 0.0f;
    #pragma unroll
    for (int mf = 0; mf < 2; ++mf)
      #pragma unroll
      for (int reg = 0; reg < 16; ++reg) cs += acc[mf][nf][reg];
    cs += __shfl_xor(cs, 32);
    if (lane < 32) atomicAdd(&col_sum[bcol + wc * 64 + nf * 32 + lane], cs);
  }
  #pragma unroll
  for (int mf = 0; mf < 2; ++mf)
    #pragma unroll
    for (int reg = 0; reg < 16; ++reg) {
      float rs = acc[mf][0][reg] + acc[mf][1][reg];
      rs += __shfl_xor(rs, 1);
      rs += __shfl_xor(rs, 2);
      rs += __shfl_xor(rs, 4);
      rs += __shfl_xor(rs, 8);
      rs += __shfl_xor(rs, 16);
      if (cl == 0)
        atomicAdd(&row_sum[brow + wr * 64 + mf * 32 + (reg & 3) + 8 * (reg >> 2) + 4 * h], rs);
    }
}

// ---------------- finalize: 3 scalars ----------------------------------------
__global__ __launch_bounds__(256) void finalize_kernel(
    const float* __restrict__ row_sum, const float* __restrict__ col_sum,
    const float* __restrict__ pos, float* __restrict__ out) {
  __shared__ float sA[4], sB[4];
  float sa = 0.0f, sb = 0.0f;
  for (int i = threadIdx.x; i < NROWS; i += 256) {
    float p = pos[i];
    sa += (INV_TAU + __logf(row_sum[i])) - p;
    sb += (INV_TAU + __logf(col_sum[i])) - p;
  }
  #pragma unroll
  for (int off = 1; off < 64; off <<= 1) {
    sa += __shfl_xor(sa, off);
    sb += __shfl_xor(sb, off);
  }
  if ((threadIdx.x & 63) == 0) { sA[threadIdx.x >> 6] = sa; sB[threadIdx.x >> 6] = sb; }
  __syncthreads();
  if (threadIdx.x == 0) {
    float ta = sA[0] + sA[1] + sA[2] + sA[3];
    float tb = sB[0] + sB[1] + sB[2] + sB[3];
    float e2t = ta / (float)NROWS;
    float t2e = tb / (float)NROWS;
    out[0] = 0.5f * (e2t + t2e);
    out[1] = e2t;
    out[2] = t2e;
  }
}

extern "C" void kernel_launch(void* const* d_in, const int* in_sizes, int n_in,
                              void* d_out, int out_size, void* d_ws, size_t ws_size,
                              hipStream_t stream) {
  const float* z_i = (const float*)d_in[0];
  const float* z_j = (const float*)d_in[1];
  float* out = (float*)d_out;
  char* ws = (char*)d_ws;
  unsigned char* ziN = (unsigned char*)ws;                         // 4 MB (panels)
  unsigned char* zjN = (unsigned char*)(ws + 4194304);             // 4 MB (panels)
  float* row_sum = (float*)(ws + 8388608);                         // 32 KB
  float* col_sum = row_sum + NROWS;                                // 32 KB (contiguous)
  float* pos     = col_sum + NROWS;                                // 32 KB

  norm_kernel<<<4096, 256, 0, stream>>>(z_i, z_j, ziN, zjN, row_sum);
  sim_lds<<<4096, 256, 0, stream>>>(ziN, zjN, row_sum, col_sum, pos);
  finalize_kernel<<<1, 256, 0, stream>>>(row_sum, col_sum, pos, out);
}

// Round 19
// 100.225 us; speedup vs baseline: 3.9863x; 3.9863x over previous
//
#include <hip/hip_runtime.h>
#include <hip/hip_fp8.h>

#define NROWS 8192
#define DDIM  512
#define INV_TAU 14.285714285714286f

typedef float f32x16 __attribute__((ext_vector_type(16)));
typedef long  longx2 __attribute__((ext_vector_type(2)));

__device__ static inline unsigned char f2e4(float f) {
  __hip_fp8_e4m3 h(f); return (unsigned char)h.__x;
}

__device__ static inline void load_lds16(const void* g, void* l) {
  __builtin_amdgcn_global_load_lds(
      (const __attribute__((address_space(1))) void*)g,
      (__attribute__((address_space(3))) void*)l, 16, 0, 0);
}

// ---------------- layout ------------------------------------------------------
// Fragment-major panels (R9-R17-verified): panel p = rows [32p,32p+32), 16KB.
// Unit u (1 KB) holds k-blocks kb=2u,2u+1 in lane order (lane = h*32 + r).
// Chunk c (8 fp8) of row r: p*16384 + (c>>2)*1024 + ((c&1)*32+r)*16 + ((c>>1)&1)*8.
// Both global_load_lds staging and ds_read_b128 frag reads are perfectly linear
// (uniform base + lane*16) -> zero bank conflicts, no swizzle.

// ---------------- normalize + zero accumulators -------------------------------
__global__ __launch_bounds__(256) void norm_kernel(
    const float* __restrict__ zi, const float* __restrict__ zj,
    unsigned char* __restrict__ ziN, unsigned char* __restrict__ zjN,
    float* __restrict__ sums /* row_sum..col_sum, 16384 floats */) {
  if (blockIdx.x < 64) sums[blockIdx.x * 256 + threadIdx.x] = 0.0f;
  int rid = blockIdx.x * 4 + (threadIdx.x >> 6);   // 0..16383
  int lane = threadIdx.x & 63;
  const float* src;
  unsigned char* dstbase;
  int row;
  if (rid < NROWS) { src = zi + (size_t)rid * DDIM; dstbase = ziN; row = rid; }
  else             { src = zj + (size_t)(rid - NROWS) * DDIM; dstbase = zjN; row = rid - NROWS; }
  float4 v0 = *(const float4*)(src + lane * 8);
  float4 v1 = *(const float4*)(src + lane * 8 + 4);
  float ss = v0.x*v0.x + v0.y*v0.y + v0.z*v0.z + v0.w*v0.w
           + v1.x*v1.x + v1.y*v1.y + v1.z*v1.z + v1.w*v1.w;
  #pragma unroll
  for (int off = 1; off < 64; off <<= 1) ss += __shfl_xor(ss, off);
  float scale = 1.0f / fmaxf(sqrtf(ss), 1e-8f);
  unsigned long long w = 0;
  w |= (unsigned long long)f2e4(v0.x * scale);
  w |= (unsigned long long)f2e4(v0.y * scale) << 8;
  w |= (unsigned long long)f2e4(v0.z * scale) << 16;
  w |= (unsigned long long)f2e4(v0.w * scale) << 24;
  w |= (unsigned long long)f2e4(v1.x * scale) << 32;
  w |= (unsigned long long)f2e4(v1.y * scale) << 40;
  w |= (unsigned long long)f2e4(v1.z * scale) << 48;
  w |= (unsigned long long)f2e4(v1.w * scale) << 56;
  int p = row >> 5, r = row & 31, c = lane;     // chunk index = lane
  *(unsigned long long*)(dstbase + (size_t)p * 16384 + (c >> 2) * 1024 +
                         ((c & 1) * 32 + r) * 16 + ((c >> 1) & 1) * 8) = w;
}

// ---------------- fused sim GEMM + exp + row/col sum + diag pos ---------------
// R13/R17-verified schedule: 128x128 block, 4 waves 2x2 (64x64/wave), BK=64,
// dbuf 32KB, stage(t+1) -> vmcnt(4) -> barrier -> ds_read+MFMA -> barrier.
// 4 blocks/CU (register-feasible max: 64 AGPR acc + ~44 VGPR).
// Diagonal epilogue also emits pos[i].
__global__ __launch_bounds__(256, 4) void sim_lds(
    const unsigned char* __restrict__ Ap, const unsigned char* __restrict__ Bp,
    float* __restrict__ row_sum, float* __restrict__ col_sum,
    float* __restrict__ pos) {
  // buffer: A[4 panels][2 units][1KB] = 8KB, B same at +8192.  2 buffers.
  __shared__ __align__(16) unsigned char lds[32768];

  const int tid  = threadIdx.x;
  const int lane = tid & 63;
  const int wid  = tid >> 6;
  const int wr   = wid >> 1, wc = wid & 1;   // 2x2 waves, 64x64 each
  const int cl   = lane & 31;                // operand row / C col
  const int h    = lane >> 5;
  // XCD-chunked swizzle (R10): xcd owns by in [8*xcd, 8*xcd+8)
  const int orig = blockIdx.x;               // 0..4095
  const int xcd  = orig & 7;
  const int seq  = orig >> 3;                // 0..511
  const int by   = xcd * 8 + (seq & 7);
  const int bx   = seq >> 3;                 // 0..63
  const int brow = by * 128, bcol = bx * 128;

  f32x16 acc[2][2] = {};

  // staging sources: wave w stages panel w of A and of B
  const unsigned char* gA = Ap + (size_t)(by * 4 + wid) * 16384 + lane * 16;
  const unsigned char* gB = Bp + (size_t)(bx * 4 + wid) * 16384 + lane * 16;
  char* ldsA = (char*)lds + wid * 2048 + lane * 16;          // + buf + kk*1024
  char* ldsB = (char*)lds + 8192 + wid * 2048 + lane * 16;

  auto stage = [&](int t) {   // tile t: units 2t, 2t+1 -> buf[t&1]
    const int buf = (t & 1) * 16384;
    const int u0  = (2 * t) << 10;
    load_lds16(gA + u0,        ldsA + buf);
    load_lds16(gA + u0 + 1024, ldsA + buf + 1024);
    load_lds16(gB + u0,        ldsB + buf);
    load_lds16(gB + u0 + 1024, ldsB + buf + 1024);
  };

  // frag-read bases (linear: unit base + lane*16)
  const char* rA = (const char*)lds + wr * 2 * 2048 + lane * 16;
  const char* rB = (const char*)lds + 8192 + wc * 2 * 2048 + lane * 16;

  // prologue: stage tile 0
  stage(0);

  #pragma unroll
  for (int t = 0; t < 8; ++t) {
    if (t < 7) {
      stage(t + 1);
      asm volatile("s_waitcnt vmcnt(4)" ::: "memory");  // tile t landed; t+1 in flight
    } else {
      asm volatile("s_waitcnt vmcnt(0)" ::: "memory");
    }
    __builtin_amdgcn_s_barrier();
    const int buf = (t & 1) * 16384;
    longx2 a[2][2], b[2][2];
    #pragma unroll
    for (int i = 0; i < 2; ++i)
      #pragma unroll
      for (int kk = 0; kk < 2; ++kk) {
        a[i][kk] = *(const longx2*)(rA + buf + i * 2048 + kk * 1024);
        b[i][kk] = *(const longx2*)(rB + buf + i * 2048 + kk * 1024);
      }
    #pragma unroll
    for (int kk = 0; kk < 2; ++kk)
      #pragma unroll
      for (int kb = 0; kb < 2; ++kb) {
        acc[0][0] = __builtin_amdgcn_mfma_f32_32x32x16_fp8_fp8(a[0][kk][kb], b[0][kk][kb], acc[0][0], 0, 0, 0);
        acc[0][1] = __builtin_amdgcn_mfma_f32_32x32x16_fp8_fp8(a[0][kk][kb], b[1][kk][kb], acc[0][1], 0, 0, 0);
        acc[1][0] = __builtin_amdgcn_mfma_f32_32x32x16_fp8_fp8(a[1][kk][kb], b[0][kk][kb], acc[1][0], 0, 0, 0);
        acc[1][1] = __builtin_amdgcn_mfma_f32_32x32x16_fp8_fp8(a[1][kk][kb], b[1][kk][kb], acc[1][1], 0, 0, 0);
      }
    __builtin_amdgcn_s_barrier();   // WAR: reads done before next overwrite
  }

  // epilogue (verified 32x32 C layout: col=cl, row=(reg&3)+8*(reg>>2)+4*h)
  // diag: pos[i] = dot * INV_TAU (identical fp8 values as lse path), e -> 0
  const float Cc = INV_TAU * 1.4426950408889634f;
  #pragma unroll
  for (int mf = 0; mf < 2; ++mf)
    #pragma unroll
    for (int nf = 0; nf < 2; ++nf) {
      int gj = bcol + wc * 64 + nf * 32 + cl;
      #pragma unroll
      for (int reg = 0; reg < 16; ++reg) {
        int gi = brow + wr * 64 + mf * 32 + (reg & 3) + 8 * (reg >> 2) + 4 * h;
        float d = acc[mf][nf][reg];
        float e = exp2f((d - 1.0f) * Cc);
        if (gi == gj) pos[gi] = d * INV_TAU;
        acc[mf][nf][reg] = (gi == gj) ? 0.0f : e;
      }
    }
  #pragma unroll
  for (int nf = 0; nf < 2; ++nf) {
    float cs = 0.0f;
    #pragma unroll
    for (int mf = 0; mf < 2; ++mf)
      #pragma unroll
      for (int reg = 0; reg < 16; ++reg) cs += acc[mf][nf][reg];
    cs += __shfl_xor(cs, 32);
    if (lane < 32) atomicAdd(&col_sum[bcol + wc * 64 + nf * 32 + lane], cs);
  }
  #pragma unroll
  for (int mf = 0; mf < 2; ++mf)
    #pragma unroll
    for (int reg = 0; reg < 16; ++reg) {
      float rs = acc[mf][0][reg] + acc[mf][1][reg];
      rs += __shfl_xor(rs, 1);
      rs += __shfl_xor(rs, 2);
      rs += __shfl_xor(rs, 4);
      rs += __shfl_xor(rs, 8);
      rs += __shfl_xor(rs, 16);
      if (cl == 0)
        atomicAdd(&row_sum[brow + wr * 64 + mf * 32 + (reg & 3) + 8 * (reg >> 2) + 4 * h], rs);
    }
}

// ---------------- finalize: 3 scalars ----------------------------------------
__global__ __launch_bounds__(256) void finalize_kernel(
    const float* __restrict__ row_sum, const float* __restrict__ col_sum,
    const float* __restrict__ pos, float* __restrict__ out) {
  __shared__ float sA[4], sB[4];
  float sa = 0.0f, sb = 0.0f;
  for (int i = threadIdx.x; i < NROWS; i += 256) {
    float p = pos[i];
    sa += (INV_TAU + __logf(row_sum[i])) - p;
    sb += (INV_TAU + __logf(col_sum[i])) - p;
  }
  #pragma unroll
  for (int off = 1; off < 64; off <<= 1) {
    sa += __shfl_xor(sa, off);
    sb += __shfl_xor(sb, off);
  }
  if ((threadIdx.x & 63) == 0) { sA[threadIdx.x >> 6] = sa; sB[threadIdx.x >> 6] = sb; }
  __syncthreads();
  if (threadIdx.x == 0) {
    float ta = sA[0] + sA[1] + sA[2] + sA[3];
    float tb = sB[0] + sB[1] + sB[2] + sB[3];
    float e2t = ta / (float)NROWS;
    float t2e = tb / (float)NROWS;
    out[0] = 0.5f * (e2t + t2e);
    out[1] = e2t;
    out[2] = t2e;
  }
}

extern "C" void kernel_launch(void* const* d_in, const int* in_sizes, int n_in,
                              void* d_out, int out_size, void* d_ws, size_t ws_size,
                              hipStream_t stream) {
  const float* z_i = (const float*)d_in[0];
  const float* z_j = (const float*)d_in[1];
  float* out = (float*)d_out;
  char* ws = (char*)d_ws;
  unsigned char* ziN = (unsigned char*)ws;                         // 4 MB (panels)
  unsigned char* zjN = (unsigned char*)(ws + 4194304);             // 4 MB (panels)
  float* row_sum = (float*)(ws + 8388608);                         // 32 KB
  float* col_sum = row_sum + NROWS;                                // 32 KB (contiguous)
  float* pos     = col_sum + NROWS;                                // 32 KB

  norm_kernel<<<4096, 256, 0, stream>>>(z_i, z_j, ziN, zjN, row_sum);
  sim_lds<<<4096, 256, 0, stream>>>(ziN, zjN, row_sum, col_sum, pos);
  finalize_kernel<<<1, 256, 0, stream>>>(row_sum, col_sum, pos, out);
}

// Round 20
// 98.996 us; speedup vs baseline: 4.0358x; 1.0124x over previous
//
#include <hip/hip_runtime.h>
#include <hip/hip_fp8.h>

#define NROWS 8192
#define DDIM  512
#define INV_TAU 14.285714285714286f

typedef float f32x16 __attribute__((ext_vector_type(16)));
typedef long  longx2 __attribute__((ext_vector_type(2)));

__device__ static inline unsigned char f2e4(float f) {
  __hip_fp8_e4m3 h(f); return (unsigned char)h.__x;
}

__device__ static inline void load_lds16(const void* g, void* l) {
  __builtin_amdgcn_global_load_lds(
      (const __attribute__((address_space(1))) void*)g,
      (__attribute__((address_space(3))) void*)l, 16, 0, 0);
}

// ---------------- layout ------------------------------------------------------
// Fragment-major panels (R9-R19-verified): panel p = rows [32p,32p+32), 16KB.
// Unit u (1 KB) holds k-blocks kb=2u,2u+1 in lane order (lane = h*32 + r).
// Chunk c (8 fp8) of row r: p*16384 + (c>>2)*1024 + ((c&1)*32+r)*16 + ((c>>1)&1)*8.
// Both global_load_lds staging and ds_read_b128 frag reads are perfectly linear
// (uniform base + lane*16) -> zero bank conflicts, no swizzle.

// ---------------- normalize + zero accumulators -------------------------------
__global__ __launch_bounds__(256) void norm_kernel(
    const float* __restrict__ zi, const float* __restrict__ zj,
    unsigned char* __restrict__ ziN, unsigned char* __restrict__ zjN,
    float* __restrict__ sums /* row_sum..col_sum, 16384 floats */) {
  if (blockIdx.x < 64) sums[blockIdx.x * 256 + threadIdx.x] = 0.0f;
  int rid = blockIdx.x * 4 + (threadIdx.x >> 6);   // 0..16383
  int lane = threadIdx.x & 63;
  const float* src;
  unsigned char* dstbase;
  int row;
  if (rid < NROWS) { src = zi + (size_t)rid * DDIM; dstbase = ziN; row = rid; }
  else             { src = zj + (size_t)(rid - NROWS) * DDIM; dstbase = zjN; row = rid - NROWS; }
  float4 v0 = *(const float4*)(src + lane * 8);
  float4 v1 = *(const float4*)(src + lane * 8 + 4);
  float ss = v0.x*v0.x + v0.y*v0.y + v0.z*v0.z + v0.w*v0.w
           + v1.x*v1.x + v1.y*v1.y + v1.z*v1.z + v1.w*v1.w;
  #pragma unroll
  for (int off = 1; off < 64; off <<= 1) ss += __shfl_xor(ss, off);
  float scale = 1.0f / fmaxf(sqrtf(ss), 1e-8f);
  unsigned long long w = 0;
  w |= (unsigned long long)f2e4(v0.x * scale);
  w |= (unsigned long long)f2e4(v0.y * scale) << 8;
  w |= (unsigned long long)f2e4(v0.z * scale) << 16;
  w |= (unsigned long long)f2e4(v0.w * scale) << 24;
  w |= (unsigned long long)f2e4(v1.x * scale) << 32;
  w |= (unsigned long long)f2e4(v1.y * scale) << 40;
  w |= (unsigned long long)f2e4(v1.z * scale) << 48;
  w |= (unsigned long long)f2e4(v1.w * scale) << 56;
  int p = row >> 5, r = row & 31, c = lane;     // chunk index = lane
  *(unsigned long long*)(dstbase + (size_t)p * 16384 + (c >> 2) * 1024 +
                         ((c & 1) * 32 + r) * 16 + ((c >> 1) & 1) * 8) = w;
}

// ---------------- fused sim GEMM + exp + row/col sum + diag pos ---------------
// BK=32 fine-phase variant at register-feasible occupancy: 128x128 block,
// 4 waves 2x2 (64x64/wave), 4-slot LDS rotation (4 x 8KB = 32KB), prefetch
// depth 3, counted vmcnt (never 0 until tail), 2 barriers/tile, 16 tiles.
// Per tile per wave: 2 stage-loads + 4 ds_read_b128 + 8 MFMAs (half the
// serial chain of BK=64 -> finer interleave across 4 co-resident blocks).
// vmcnt ledger: enter iter t with {t+2,t+3} outstanding; stage(t+3) -> 6;
// vmcnt(4) drains t+1 (t landed two drains ago).  Tail: 14->2, 15->0.
__global__ __launch_bounds__(256, 4) void sim_lds(
    const unsigned char* __restrict__ Ap, const unsigned char* __restrict__ Bp,
    float* __restrict__ row_sum, float* __restrict__ col_sum,
    float* __restrict__ pos) {
  // slot s (8KB): A[4 panels][1KB] at s*8192, B[4 panels][1KB] at s*8192+4096.
  __shared__ __align__(16) unsigned char lds[32768];

  const int tid  = threadIdx.x;
  const int lane = tid & 63;
  const int wid  = tid >> 6;
  const int wr   = wid >> 1, wc = wid & 1;   // 2x2 waves, 64x64 each
  const int cl   = lane & 31;                // operand row / C col
  const int h    = lane >> 5;
  // XCD-chunked swizzle (R10): xcd owns by in [8*xcd, 8*xcd+8)
  const int orig = blockIdx.x;               // 0..4095
  const int xcd  = orig & 7;
  const int seq  = orig >> 3;                // 0..511
  const int by   = xcd * 8 + (seq & 7);
  const int bx   = seq >> 3;                 // 0..63
  const int brow = by * 128, bcol = bx * 128;

  f32x16 acc[2][2] = {};

  // staging sources: wave w stages panel w of A and of B (unit t each tile)
  const unsigned char* gA = Ap + (size_t)(by * 4 + wid) * 16384 + lane * 16;
  const unsigned char* gB = Bp + (size_t)(bx * 4 + wid) * 16384 + lane * 16;
  char* ldsA = (char*)lds + wid * 1024 + lane * 16;          // + slot*8192
  char* ldsB = (char*)lds + 4096 + wid * 1024 + lane * 16;

  auto stage = [&](int t) {   // tile t = unit t -> slot t&3
    const int sb = (t & 3) * 8192;
    const int u0 = t << 10;
    load_lds16(gA + u0, ldsA + sb);
    load_lds16(gB + u0, ldsB + sb);
  };

  // frag-read bases (linear: unit base + lane*16)
  const char* rA = (const char*)lds + wr * 2 * 1024 + lane * 16;
  const char* rB = (const char*)lds + 4096 + wc * 2 * 1024 + lane * 16;

  // prologue: stage tiles 0,1,2 (6 loads outstanding)
  stage(0);
  stage(1);
  stage(2);

  #pragma unroll
  for (int t = 0; t < 16; ++t) {
    if (t < 13) stage(t + 3);
    if (t <= 13)      asm volatile("s_waitcnt vmcnt(4)" ::: "memory");
    else if (t == 14) asm volatile("s_waitcnt vmcnt(2)" ::: "memory");
    else              asm volatile("s_waitcnt vmcnt(0)" ::: "memory");
    __builtin_amdgcn_s_barrier();
    const int sb = (t & 3) * 8192;
    longx2 a[2], b[2];
    #pragma unroll
    for (int i = 0; i < 2; ++i) {
      a[i] = *(const longx2*)(rA + sb + i * 1024);
      b[i] = *(const longx2*)(rB + sb + i * 1024);
    }
    #pragma unroll
    for (int kb = 0; kb < 2; ++kb) {
      acc[0][0] = __builtin_amdgcn_mfma_f32_32x32x16_fp8_fp8(a[0][kb], b[0][kb], acc[0][0], 0, 0, 0);
      acc[0][1] = __builtin_amdgcn_mfma_f32_32x32x16_fp8_fp8(a[0][kb], b[1][kb], acc[0][1], 0, 0, 0);
      acc[1][0] = __builtin_amdgcn_mfma_f32_32x32x16_fp8_fp8(a[1][kb], b[0][kb], acc[1][0], 0, 0, 0);
      acc[1][1] = __builtin_amdgcn_mfma_f32_32x32x16_fp8_fp8(a[1][kb], b[1][kb], acc[1][1], 0, 0, 0);
    }
    __builtin_amdgcn_s_barrier();   // WAR: reads done before slot reuse (t+4)
  }

  // epilogue (verified 32x32 C layout: col=cl, row=(reg&3)+8*(reg>>2)+4*h)
  // diag: pos[i] = dot * INV_TAU (identical fp8 values as lse path), e -> 0
  const float Cc = INV_TAU * 1.4426950408889634f;
  #pragma unroll
  for (int mf = 0; mf < 2; ++mf)
    #pragma unroll
    for (int nf = 0; nf < 2; ++nf) {
      int gj = bcol + wc * 64 + nf * 32 + cl;
      #pragma unroll
      for (int reg = 0; reg < 16; ++reg) {
        int gi = brow + wr * 64 + mf * 32 + (reg & 3) + 8 * (reg >> 2) + 4 * h;
        float d = acc[mf][nf][reg];
        float e = exp2f((d - 1.0f) * Cc);
        if (gi == gj) pos[gi] = d * INV_TAU;
        acc[mf][nf][reg] = (gi == gj) ? 0.0f : e;
      }
    }
  #pragma unroll
  for (int nf = 0; nf < 2; ++nf) {
    float cs = 0.0f;
    #pragma unroll
    for (int mf = 0; mf < 2; ++mf)
      #pragma unroll
      for (int reg = 0; reg < 16; ++reg) cs += acc[mf][nf][reg];
    cs += __shfl_xor(cs, 32);
    if (lane < 32) atomicAdd(&col_sum[bcol + wc * 64 + nf * 32 + lane], cs);
  }
  #pragma unroll
  for (int mf = 0; mf < 2; ++mf)
    #pragma unroll
    for (int reg = 0; reg < 16; ++reg) {
      float rs = acc[mf][0][reg] + acc[mf][1][reg];
      rs += __shfl_xor(rs, 1);
      rs += __shfl_xor(rs, 2);
      rs += __shfl_xor(rs, 4);
      rs += __shfl_xor(rs, 8);
      rs += __shfl_xor(rs, 16);
      if (cl == 0)
        atomicAdd(&row_sum[brow + wr * 64 + mf * 32 + (reg & 3) + 8 * (reg >> 2) + 4 * h], rs);
    }
}

// ---------------- finalize: 3 scalars ----------------------------------------
__global__ __launch_bounds__(256) void finalize_kernel(
    const float* __restrict__ row_sum, const float* __restrict__ col_sum,
    const float* __restrict__ pos, float* __restrict__ out) {
  __shared__ float sA[4], sB[4];
  float sa = 0.0f, sb = 0.0f;
  for (int i = threadIdx.x; i < NROWS; i += 256) {
    float p = pos[i];
    sa += (INV_TAU + __logf(row_sum[i])) - p;
    sb += (INV_TAU + __logf(col_sum[i])) - p;
  }
  #pragma unroll
  for (int off = 1; off < 64; off <<= 1) {
    sa += __shfl_xor(sa, off);
    sb += __shfl_xor(sb, off);
  }
  if ((threadIdx.x & 63) == 0) { sA[threadIdx.x >> 6] = sa; sB[threadIdx.x >> 6] = sb; }
  __syncthreads();
  if (threadIdx.x == 0) {
    float ta = sA[0] + sA[1] + sA[2] + sA[3];
    float tb = sB[0] + sB[1] + sB[2] + sB[3];
    float e2t = ta / (float)NROWS;
    float t2e = tb / (float)NROWS;
    out[0] = 0.5f * (e2t + t2e);
    out[1] = e2t;
    out[2] = t2e;
  }
}

extern "C" void kernel_launch(void* const* d_in, const int* in_sizes, int n_in,
                              void* d_out, int out_size, void* d_ws, size_t ws_size,
                              hipStream_t stream) {
  const float* z_i = (const float*)d_in[0];
  const float* z_j = (const float*)d_in[1];
  float* out = (float*)d_out;
  char* ws = (char*)d_ws;
  unsigned char* ziN = (unsigned char*)ws;                         // 4 MB (panels)
  unsigned char* zjN = (unsigned char*)(ws + 4194304);             // 4 MB (panels)
  float* row_sum = (float*)(ws + 8388608);                         // 32 KB
  float* col_sum = row_sum + NROWS;                                // 32 KB (contiguous)
  float* pos     = col_sum + NROWS;                                // 32 KB

  norm_kernel<<<4096, 256, 0, stream>>>(z_i, z_j, ziN, zjN, row_sum);
  sim_lds<<<4096, 256, 0, stream>>>(ziN, zjN, row_sum, col_sum, pos);
  finalize_kernel<<<1, 256, 0, stream>>>(row_sum, col_sum, pos, out);
}